// Round 12
// baseline (81.000 us; speedup 1.0000x reference)
//
#include <hip/hip_runtime.h>

typedef __bf16 bf16x8 __attribute__((ext_vector_type(8)));
typedef float  f32x4  __attribute__((ext_vector_type(4)));
typedef unsigned short u16;

#define NB    512
#define SEQ   128
#define EMB   300
#define NT_TOT 19               // N = 304 unified (300 filters padded), tiles of 16
#define KT_TOT 50               // K = 1600 = 50*32
#define WU_ELEMS (304 * 1600)   // 486400 bf16
#define OFF_FEATS (WU_ELEMS * 2)   // 972800 B; feats = 512*300 f32 after weights

// Per-wave-contiguous B layout: wave g in {0,1,2,3} owns NTW(g)=5,5,5,4 tiles.
// Region base (elems): g*128000 (g3 region is 102400). Within region:
//   elem = (kt*NTW + tloc)*512 + lane*8 + j
#define GRP_ELEMS 128000        // 50 kt * 5 tiles * 512

// A tile: 68 rows + 1 guard, 320 bf16/row, stride 640 B, XOR swizzle ((r&7)<<4)
// -- the r1/r4/r6/r8/r11-verified ZERO-conflict geometry.
#define AROW 640
#define A_BYTES (69 * AROW)     // 44160 -> 3 blocks/CU (132.5 KB)

__device__ __forceinline__ u16 f2bf(float f) {
  unsigned u = __builtin_bit_cast(unsigned, f);
  return (u16)((u + 0x7fffu + ((u >> 16) & 1u)) >> 16);   // RNE
}

// Unified weights, MFMA-B-fragment order, per-wave-contiguous (see above).
//   logical W[f = nt*16 + (lane&15)][kk = kt*32 + (lane>>4)*8 + j]
// kk -> (dk = kk/320, e = kk%320); k=5-aligned window (x rows s-2..s+2):
//   f<100: w3 valid dk 2..4 ; f<200: w4 valid dk 1..4 ; f<300: w5 dk 0..4
__global__ void prep_weights(const float* __restrict__ w3, const float* __restrict__ w4,
                             const float* __restrict__ w5, u16* __restrict__ wu) {
  int idx = blockIdx.x * blockDim.x + threadIdx.x;
  if (idx >= WU_ELEMS) return;
  int j = idx & 7, l = (idx >> 3) & 63, t = idx >> 9;
  int nt = t % NT_TOT, kt = t / NT_TOT;
  int f  = nt * 16 + (l & 15);
  int kk = kt * 32 + ((l >> 4) << 3) + j;
  int dk = kk / 320, e = kk - dk * 320;
  float v = 0.f;
  if (f < 300 && e < 300) {
    if (f < 100)      { if (dk >= 2) v = w3[(f * 3 + dk - 2) * 300 + e]; }
    else if (f < 200) { if (dk >= 1) v = w4[((f - 100) * 4 + dk - 1) * 300 + e]; }
    else              {              v = w5[((f - 200) * 5 + dk) * 300 + e]; }
  }
  int g    = nt / 5;                       // 0..3
  int tloc = nt - g * 5;
  int ntw  = (g == 3) ? 4 : 5;
  wu[g * GRP_ELEMS + (kt * ntw + tloc) * 512 + (l << 3) + j] = f2bf(v);
}

// K-loop: A single-set (ds_read right before the burst -- 3 waves/SIMD hide the
// latency), B global->VGPR double-buffered 2 deep from a per-wave CONTIGUOUS
// stream (pointer + immediate offsets). No LDS writes in loop, no manual fences,
// no setprio. All waits compiler-counted.
template<int NTW>
__device__ __forceinline__ void kloop_epi(const char* xs, const char* gB0,
                                          int ntb, int l, int b, int s0,
                                          const float* __restrict__ b3,
                                          const float* __restrict__ b4,
                                          const float* __restrict__ b5,
                                          float* __restrict__ feats) {
  const int lo = l & 15, hi = l >> 4;

  f32x4 acc[4][NTW];
  #pragma unroll
  for (int mt = 0; mt < 4; ++mt)
    #pragma unroll
    for (int j = 0; j < NTW; ++j) acc[mt][j] = (f32x4){0.f, 0.f, 0.f, 0.f};

  bf16x8 aa[4], bC[NTW], bN[NTW];

  // B(0) -> bC, B(1) -> bN; thereafter load B(kt+2) into the just-consumed set.
  const char* gB = gB0 + l * 16;
  #pragma unroll
  for (int j = 0; j < NTW; ++j) bC[j] = *reinterpret_cast<const bf16x8*>(gB + j * 1024);
  #pragma unroll
  for (int j = 0; j < NTW; ++j) bN[j] = *reinterpret_cast<const bf16x8*>(gB + (NTW + j) * 1024);
  gB += 2 * NTW * 1024;

  // A base: row r = mt*16 + lo + dk, addr = (r*640 + hi*16 + eg*64) ^ ((r&7)<<4)
  int abase[4];
  #pragma unroll
  for (int mt = 0; mt < 4; ++mt) abase[mt] = (mt * 16 + lo) * AROW + hi * 16;

  // Per step: read A(kt) -> MFMA(kt) -> load B(kt+2) into the consumed B set.
#define STEP(AOFF, SW, Bcon) {                                                 \
    _Pragma("unroll") for (int mt = 0; mt < 4; ++mt)                           \
      aa[mt] = *reinterpret_cast<const bf16x8*>(xs + ((abase[mt] + (AOFF)) ^ (SW))); \
    _Pragma("unroll") for (int mt = 0; mt < 4; ++mt)                           \
    _Pragma("unroll") for (int j = 0; j < NTW; ++j)                            \
      acc[mt][j] = __builtin_amdgcn_mfma_f32_16x16x32_bf16(aa[mt], Bcon[j],    \
                                                           acc[mt][j], 0, 0, 0); \
    _Pragma("unroll") for (int j = 0; j < NTW; ++j)                            \
      Bcon[j] = *reinterpret_cast<const bf16x8*>(gB + j * 1024);               \
    gB += NTW * 1024; }

  #pragma unroll 1
  for (int dk = 0; dk < 5; ++dk) {
    const int sw = ((lo + dk) & 7) << 4;        // row-XOR swizzle, constant per dk
    STEP(  0, sw, bC)   // eg 0
    STEP( 64, sw, bN)   // eg 1
    STEP(128, sw, bC)   // eg 2
    STEP(192, sw, bN)   // eg 3
    STEP(256, sw, bC)   // eg 4
    STEP(320, sw, bN)   // eg 5
    STEP(384, sw, bC)   // eg 6
    STEP(448, sw, bN)   // eg 7
    STEP(512, sw, bC)   // eg 8
    STEP(576, sw, bN)   // eg 9
    #pragma unroll
    for (int mt = 0; mt < 4; ++mt) abase[mt] += AROW;
  }
  // tail over-reads (B(50),B(51) land within ws) are never consumed
#undef STEP

  // epilogue: bias + relu + masked max over this block's 64 s-positions
  #pragma unroll
  for (int j = 0; j < NTW; ++j) {
    int f = (ntb + j) * 16 + lo;
    if (f < 300) {
      float bia  = (f < 100) ? b3[f] : (f < 200) ? b4[f - 100] : b5[f - 200];
      int   sval = (f < 100) ? 126   : (f < 200) ? 127         : 128;
      float cmax = 0.f;                            // relu floor
      #pragma unroll
      for (int mt = 0; mt < 4; ++mt)
        #pragma unroll
        for (int ii = 0; ii < 4; ++ii) {
          int s = s0 + mt * 16 + hi * 4 + ii;      // C/D: row=(l>>4)*4+ii, col=l&15
          float v = acc[mt][j][ii] + bia;
          if (s < sval) cmax = fmaxf(cmax, v);
        }
      cmax = fmaxf(cmax, __shfl_xor(cmax, 16));
      cmax = fmaxf(cmax, __shfl_xor(cmax, 32));
      if (hi == 0)
        atomicMax((int*)&feats[b * 300 + f], __float_as_int(fmaxf(cmax, 0.f)));
    }
  }
}

// Block = (sample, s-half): M=64, N=304, K=1600. 4 waves, wave = 4M x 5N (w3: 4N).
// A staged once in LDS (640-stride + XOR swizzle, 0-conflict verified); B global->reg
// dbuf from per-wave contiguous stream; barrier-free K-loop; 3 blocks/CU target
// (regs/wave must be <= 170 -- A single-set keeps us under).
__global__ __launch_bounds__(256, 3)
void conv_max_kernel(const float* __restrict__ x, const u16* __restrict__ wu,
                     const float* __restrict__ b3, const float* __restrict__ b4,
                     const float* __restrict__ b5, float* __restrict__ feats) {
  __shared__ __align__(16) char xs[A_BYTES];
  const int bid = blockIdx.x;
  const int b = bid >> 1, s0 = (bid & 1) * 64;
  const int tid = threadIdx.x;
  const int l = tid & 63, w = tid >> 6;
  const float* xb = x + (size_t)b * (SEQ * EMB);
  const char*  wB = (const char*)wu + w * (GRP_ELEMS * 2);

  // stage A: rows s0-2 .. s0+65 (68), 640 B stride, XOR swizzle (verified)
  for (int t = tid; t < 68 * 80; t += 256) {
    int r = t / 80, cg = t - r * 80;
    int xr = s0 - 2 + r;
    float4 v = make_float4(0.f, 0.f, 0.f, 0.f);
    if (xr >= 0 && xr < SEQ && cg < 75)
      v = *reinterpret_cast<const float4*>(xb + xr * EMB + cg * 4);
    ushort4 h;
    h.x = f2bf(v.x); h.y = f2bf(v.y); h.z = f2bf(v.z); h.w = f2bf(v.w);
    int boff = (r * AROW + cg * 8) ^ ((r & 7) << 4);
    *reinterpret_cast<ushort4*>(xs + boff) = h;
  }
  __syncthreads();   // the only barrier: A visible to all 4 waves

  if (w == 3) kloop_epi<4>(xs, wB, 15, l, b, s0, b3, b4, b5, feats);
  else        kloop_epi<5>(xs, wB, w * 5, l, b, s0, b3, b4, b5, feats);
}

// feats[512,300] @ Wfc[5,300]^T + bfc -> log_softmax. One wave per row.
__global__ void fc_kernel(const float* __restrict__ feats, const float* __restrict__ Wfc,
                          const float* __restrict__ bfc, float* __restrict__ out) {
  const int b = blockIdx.x, l = threadIdx.x;
  float acc[5] = {0.f, 0.f, 0.f, 0.f, 0.f};
  for (int e = l; e < 300; e += 64) {
    float fv = feats[b * 300 + e];
    #pragma unroll
    for (int c = 0; c < 5; ++c) acc[c] += fv * Wfc[c * 300 + e];
  }
  #pragma unroll
  for (int off = 32; off; off >>= 1) {
    #pragma unroll
    for (int c = 0; c < 5; ++c) acc[c] += __shfl_down(acc[c], off);
  }
  if (l == 0) {
    float lg[5], m = -1e30f;
    #pragma unroll
    for (int c = 0; c < 5; ++c) { lg[c] = acc[c] + bfc[c]; m = fmaxf(m, lg[c]); }
    float se = 0.f;
    #pragma unroll
    for (int c = 0; c < 5; ++c) se += expf(lg[c] - m);
    float ls = logf(se);
    #pragma unroll
    for (int c = 0; c < 5; ++c) out[b * 5 + c] = lg[c] - m - ls;
  }
}

extern "C" void kernel_launch(void* const* d_in, const int* in_sizes, int n_in,
                              void* d_out, int out_size, void* d_ws, size_t ws_size,
                              hipStream_t stream) {
  const float* x   = (const float*)d_in[0];
  const float* w3  = (const float*)d_in[1];
  const float* b3  = (const float*)d_in[2];
  const float* w4  = (const float*)d_in[3];
  const float* b4  = (const float*)d_in[4];
  const float* w5  = (const float*)d_in[5];
  const float* b5  = (const float*)d_in[6];
  const float* Wfc = (const float*)d_in[7];
  const float* bfc = (const float*)d_in[8];
  float* out = (float*)d_out;

  u16*   wu    = (u16*)d_ws;
  float* feats = (float*)((char*)d_ws + OFF_FEATS);

  hipMemsetAsync(feats, 0, NB * 300 * sizeof(float), stream);  // atomicMax target

  prep_weights<<<(WU_ELEMS + 255) / 256, 256, 0, stream>>>(w3, w4, w5, wu);
  conv_max_kernel<<<NB * 2, 256, 0, stream>>>(x, wu, b3, b4, b5, feats);
  fc_kernel<<<NB, 64, 0, stream>>>(feats, Wfc, bfc, out);
}